// Round 7
// baseline (42.938 us; speedup 1.0000x reference)
//
#include <hip/hip_runtime.h>

#define NCAM   6
#define FHW    72        // FH*FW
#define EMBED  128
#define NG     432       // gaussians per scale
#define THRESH 0.01f
#define AMIN   (1.0f/255.0f)
#define NBLK   1139      // s0:40 | s1:160 | s2:314 | s3:625
// block layout (long s0/s1 poles first):
//   [0,40)      s0: stripe=i>>2, chgroup=i&3   (CG=32)
//   [40,200)    s1: stripe=i>>2, chgroup=i&3   (CG=32)
//   [200,514)   s2: stripe=i>>1, chgroup=i&1   (CG=64)
//   [514,1139)  s3: stripe=i,    chgroup=0     (CG=128)
//   1139        num_gaussians reduction

struct Args {
    const float* feat[4];
    const float* mean[4];
    const float* unc[4];
    const float* opac[4];
    float* out;
};

// One stripe = 64 consecutive flat pixels of one scale. Wave = 64 px x CHPER ch.
// Per-lane-private transmittance chain; params ballot-compacted straight from
// registers into LDS; features chunk-staged (32 entries) into LDS, read
// wave-uniform (broadcast). Stores: per-channel 256B contiguous runs.
template<int H_, int CG_>
__device__ __forceinline__ void render_body(
    const float* __restrict__ feat, const float* __restrict__ mean,
    const float* __restrict__ unc,  const float* __restrict__ opac,
    float* __restrict__ o, int stripe, int chg, int t,
    float4* cp4, float2* cp2, int* coff, int* cnt, float* sf)
{
    constexpr int P_    = H_ * H_;
    constexpr int CHPER = CG_ / 4;   // channels per wave
    constexpr int CGD8  = CG_ / 8;   // channels per staging thread
    constexpr int NF4   = CGD8 / 4;  // float4s per staging thread

    int lane = t & 63, wv = t >> 6;
    const float sh = H_ * 0.01f;

    // stripe bounding box (block-uniform)
    int p0 = stripe * 64;
    int pend = min(p0 + 63, P_ - 1);
    int r0 = p0 / H_, r1 = pend / H_;
    float r0f = (float)r0, r1f = (float)r1;
    float c0f, c1f;
    if (r1 > r0) { c0f = 0.f; c1f = (float)(H_ - 1); }
    else         { c0f = (float)(p0 - r0 * H_); c1f = (float)(pend - r0 * H_); }

    // ---- prologue: params in regs + ballot-compact cull into LDS ----
    float v_pr[2], v_pc[2], v_qa[2], v_qb[2], v_qc[2], v_ok[2];
    int v_off[2], v_rnk[2];
    bool v_act[2];
    #pragma unroll
    for (int pp = 0; pp < 2; pp++) {
        int j = pp * 256 + t;
        bool act = false;
        float pr = 0.f, pc = 0.f, qa = 0.f, qb = 0.f, qc = 0.f, ok = 0.f;
        int off = 0;
        if (j < NG) {
            float m0 = mean[j*3+0], m1 = mean[j*3+1];
            float u00 = fmaxf(unc[j*9+0], 1.f);
            float u01 = fmaxf(unc[j*9+1], 1.f);
            float u11 = fmaxf(unc[j*9+4], 1.f);
            float op = opac[j];
            pr = -sh*m1 + H_*0.5f;
            pc = -sh*m0 + H_*0.5f;
            float va = sh*sh*u11 + 0.3f;
            float vb = sh*sh*u01;
            float vc = sh*sh*u00 + 0.3f;
            float det = va*vc - vb*vb;
            if (op > THRESH && det > 0.f) {
                float inv = 1.f/det;
                qa = 0.5f*vc*inv;   // dr^2 coeff
                qc = 0.5f*va*inv;   // dc^2 coeff
                qb = vb*inv;        // dr*dc coeff
                ok = op;
                float thr = __logf(255.f*op);          // alpha >= 1/255 level set
                float Rr = sqrtf(2.f*va*thr) + 1e-2f;  // max |dr| on level set
                float Rc = sqrtf(2.f*vc*thr) + 1e-2f;  // max |dc| on level set
                act = (pr >= r0f-Rr) && (pr <= r1f+Rr) &&
                      (pc >= c0f-Rc) && (pc <= c1f+Rc);
            }
            int cam = j / FHW;
            off = cam * (EMBED*FHW) + (j - cam*FHW);   // feat addr of (cam, d=0, hw)
        }
        unsigned long long m = __ballot(act);
        v_act[pp] = act;
        v_rnk[pp] = __popcll(m & ((1ull << lane) - 1ull));
        v_pr[pp]=pr; v_pc[pp]=pc; v_qa[pp]=qa; v_qb[pp]=qb;
        v_qc[pp]=qc; v_ok[pp]=ok; v_off[pp]=off;
        if (lane == 0) cnt[pp*4 + wv] = __popcll(m);
    }
    __syncthreads();
    int c8[8];
    #pragma unroll
    for (int i = 0; i < 8; i++) c8[i] = cnt[i];
    int len = 0;
    #pragma unroll
    for (int i = 0; i < 8; i++) len += c8[i];
    #pragma unroll
    for (int pp = 0; pp < 2; pp++) {
        int slot = pp*4 + wv;
        int pre = 0;
        #pragma unroll
        for (int i = 0; i < 8; i++) pre += (i < slot) ? c8[i] : 0;
        if (v_act[pp]) {
            int idx = pre + v_rnk[pp];
            cp4[idx]  = make_float4(v_pr[pp], v_pc[pp], v_qa[pp], v_qb[pp]);
            cp2[idx]  = make_float2(v_qc[pp], v_ok[pp]);
            coff[idx] = v_off[pp];
        }
    }
    __syncthreads();

    // ---- main loop ----
    int p = p0 + lane;
    int row = p / H_, col = p - row * H_;          // compile-time H_: magic mul
    float frow = (float)row, fcol = (float)col;
    int e = t >> 3, sub = t & 7;                   // staging: entry e, ch-slice sub
    int chbase = chg * CG_;
    int wvch = wv * CHPER;

    float acc[CHPER];
    #pragma unroll
    for (int i = 0; i < CHPER; i++) acc[i] = 0.f;
    float T = 1.f;
    float4 fst4[NF4];

    auto SLOAD = [&](int c0, int kmax) {
        if (e < kmax) {
            const float* q = feat + coff[c0 + e] + (chbase + sub * CGD8) * FHW;
            #pragma unroll
            for (int i = 0; i < NF4; i++) {
                fst4[i].x = q[(i*4+0)*FHW];
                fst4[i].y = q[(i*4+1)*FHW];
                fst4[i].z = q[(i*4+2)*FHW];
                fst4[i].w = q[(i*4+3)*FHW];
            }
        }
    };
    auto SWRITE = [&](int kmax) {
        if (e < kmax) {
            #pragma unroll
            for (int i = 0; i < NF4; i++)
                *reinterpret_cast<float4*>(&sf[e*CG_ + sub*CGD8 + i*4]) = fst4[i];
        }
    };

    if (len > 0) {
        SLOAD(0, min(32, len));
        SWRITE(min(32, len));
        __syncthreads();
        for (int c0 = 0; c0 < len; c0 += 32) {
            int kmax = min(32, len - c0);
            int nxt = c0 + 32;
            bool more = nxt < len;
            int kmn = more ? min(32, len - nxt) : 0;
            if (more) SLOAD(nxt, kmn);              // scattered L2 gather, hidden
            #pragma unroll 2
            for (int k = 0; k < kmax; k++) {        // all-reg/LDS-broadcast composite
                float4 pa = cp4[c0 + k];
                float2 pb = cp2[c0 + k];
                float dr = pa.x - frow, dc = pa.y - fcol;
                float pw = pa.w*dr*dc - pa.z*dr*dr - pb.x*dc*dc;
                float aL = 0.f;
                if (pw <= 0.f) {
                    aL = fminf(pb.y * __expf(pw), 0.99f);
                    aL = (aL >= AMIN) ? aL : 0.f;
                }
                float w = aL * T;
                T *= (1.f - aL);
                const float* frp = &sf[k*CG_ + wvch];
                #pragma unroll
                for (int i = 0; i < CHPER; i += 4) {
                    float4 f = *reinterpret_cast<const float4*>(frp + i);
                    acc[i]   += w*f.x; acc[i+1] += w*f.y;
                    acc[i+2] += w*f.z; acc[i+3] += w*f.w;
                }
            }
            __syncthreads();                         // all waves done with sf
            if (more) { SWRITE(kmn); __syncthreads(); }
        }
    }

    // ---- store: per-channel 256B contiguous runs ----
    if (p < P_) {
        #pragma unroll
        for (int i = 0; i < CHPER; i++)
            o[(chbase + wvch + i) * P_ + p] = acc[i];
    }
}

__global__ __launch_bounds__(256, 4) void gauss_render(Args a)
{
    __shared__ float4 cp4[NG];
    __shared__ float2 cp2[NG];
    __shared__ int    coff[NG];
    __shared__ int    cnt[8];
    __shared__ __align__(16) float sf[32 * EMBED];

    int bb = blockIdx.x, t = threadIdx.x;

    if (bb == NBLK) {                    // num_gaussians
        __shared__ float red[256];
        float c = 0.f;
        for (int s = 0; s < 4; s++)
            for (int i = t; i < NG; i += 256)
                c += (a.opac[s][i] > THRESH) ? 1.f : 0.f;
        red[t] = c;
        __syncthreads();
        for (int st = 128; st > 0; st >>= 1) {
            if (t < st) red[t] += red[t + st];
            __syncthreads();
        }
        if (t == 0) a.out[6800000] = red[0];
        return;
    }

    if (bb < 40) {
        int i = bb;
        render_body<25, 32>(a.feat[0], a.mean[0], a.unc[0], a.opac[0],
                            a.out, i >> 2, i & 3, t, cp4, cp2, coff, cnt, sf);
    } else if (bb < 200) {
        int i = bb - 40;
        render_body<50, 32>(a.feat[1], a.mean[1], a.unc[1], a.opac[1],
                            a.out + 80000, i >> 2, i & 3, t, cp4, cp2, coff, cnt, sf);
    } else if (bb < 514) {
        int i = bb - 200;
        render_body<100, 64>(a.feat[2], a.mean[2], a.unc[2], a.opac[2],
                             a.out + 400000, i >> 1, i & 1, t, cp4, cp2, coff, cnt, sf);
    } else {
        int i = bb - 514;
        render_body<200, 128>(a.feat[3], a.mean[3], a.unc[3], a.opac[3],
                              a.out + 1680000, i, 0, t, cp4, cp2, coff, cnt, sf);
    }
}

extern "C" void kernel_launch(void* const* d_in, const int* in_sizes, int n_in,
                              void* d_out, int out_size, void* d_ws, size_t ws_size,
                              hipStream_t stream)
{
    Args a;
    for (int s = 0; s < 4; s++) {
        a.feat[s] = (const float*)d_in[4 * s + 0];
        a.mean[s] = (const float*)d_in[4 * s + 1];
        a.unc[s]  = (const float*)d_in[4 * s + 2];
        a.opac[s] = (const float*)d_in[4 * s + 3];
    }
    a.out = (float*)d_out;

    gauss_render<<<NBLK + 1, 256, 0, stream>>>(a);
}

// Round 8
// 36.971 us; speedup vs baseline: 1.1614x; 1.1614x over previous
//
#include <hip/hip_runtime.h>

#define NCAM   6
#define FHW    72        // FH*FW
#define EMBED  128
#define NG     432       // gaussians per scale
#define THRESH 0.01f
#define AMIN   (1.0f/255.0f)
#define NTILES 891
#define TC     432       // per-tile list capacity
// tiles are 4 rows x 16 cols:
// s0: 7x2=14 [0,14) H=25 | s1: 13x4=52 [14,66) H=50
// s2: 25x7=175 [66,241) H=100 | s3: 50x13=650 [241,891) H=200

struct Args {
    const float* feat[4];
    const float* mean[4];
    const float* unc[4];
    const float* opac[4];
};

__device__ __forceinline__ void tile_decode(int g, int& s, int& H, int& band, int& chunk)
{
    int tb;
    if (g < 14)       { s = 0; H = 25;  tb = g;       chunk = tb & 1;  band = tb >> 1; }
    else if (g < 66)  { s = 1; H = 50;  tb = g - 14;  chunk = tb & 3;  band = tb >> 2; }
    else if (g < 241) { s = 2; H = 100; tb = g - 66;  band = tb / 7;   chunk = tb - band * 7; }
    else              { s = 3; H = 200; tb = g - 241; band = tb / 13;  chunk = tb - band * 13; }
}

// K1: blocks [0,891) = tile list+params+w-scan; [891,915) = ft transpose; 915 = count
__global__ __launch_bounds__(256) void prep(Args a, float* __restrict__ ft,
                                            int* __restrict__ tlen,
                                            unsigned* __restrict__ tofs,
                                            float* __restrict__ w_ws,
                                            float* __restrict__ out)
{
    int b = blockIdx.x, t = threadIdx.x;
    if (b < NTILES) {
        __shared__ float4 e0[TC];     // pr, pc, qa, qb
        __shared__ float4 e1[TC];     // qc, ok, -, -
        __shared__ int s_cnt[8];
        int g = b;
        int s, H, band, chunk;
        tile_decode(g, s, H, band, chunk);
        int lane = t & 63, wv = t >> 6;
        float sh = H * 0.01f;
        float r0f = (float)(band * 4), r1f = (float)min(band * 4 + 3, H - 1);
        float c0f = (float)(chunk * 16), c1f = (float)min(chunk * 16 + 15, H - 1);
        const float* mean = a.mean[s];
        const float* unc  = a.unc[s];
        const float* opac = a.opac[s];

        bool v_act[2]; int v_rnk[2];
        float v_pr[2], v_pc[2], v_qa[2], v_qb[2], v_qc[2], v_ok[2];
        #pragma unroll
        for (int pp = 0; pp < 2; pp++) {
            int j = pp * 256 + t;
            bool act = false;
            float pr = 0.f, pc = 0.f, qa = 0.f, qb = 0.f, qc = 0.f, ok = 0.f;
            if (j < NG) {
                float m0 = mean[j*3+0], m1 = mean[j*3+1];
                float u00 = fmaxf(unc[j*9+0], 1.f);
                float u01 = fmaxf(unc[j*9+1], 1.f);
                float u11 = fmaxf(unc[j*9+4], 1.f);
                float op = opac[j];
                pr = -sh*m1 + H*0.5f;
                pc = -sh*m0 + H*0.5f;
                float va = sh*sh*u11 + 0.3f;
                float vb = sh*sh*u01;
                float vc = sh*sh*u00 + 0.3f;
                float det = va*vc - vb*vb;
                if (op > THRESH && det > 0.f) {
                    float inv = 1.f/det;
                    qa = 0.5f*vc*inv;                      // dr^2 coeff
                    qc = 0.5f*va*inv;                      // dc^2 coeff
                    qb = vb*inv;                           // dr*dc coeff
                    ok = op;
                    float thr = __logf(255.f*op);          // alpha >= 1/255 level set
                    float Rr = sqrtf(2.f*va*thr) + 1e-2f;  // max |dr| on level set
                    float Rc = sqrtf(2.f*vc*thr) + 1e-2f;  // max |dc| on level set
                    act = (pr >= r0f-Rr) && (pr <= r1f+Rr) &&
                          (pc >= c0f-Rc) && (pc <= c1f+Rc);
                }
            }
            unsigned long long m = __ballot(act);
            v_act[pp] = act;
            v_rnk[pp] = __popcll(m & ((1ull << lane) - 1ull));
            v_pr[pp]=pr; v_pc[pp]=pc; v_qa[pp]=qa; v_qb[pp]=qb; v_qc[pp]=qc; v_ok[pp]=ok;
            if (lane == 0) s_cnt[pp*4 + wv] = __popcll(m);
        }
        __syncthreads();
        int c8[8];
        #pragma unroll
        for (int i = 0; i < 8; i++) c8[i] = s_cnt[i];
        int len = 0;
        #pragma unroll
        for (int i = 0; i < 8; i++) len += c8[i];
        #pragma unroll
        for (int pp = 0; pp < 2; pp++) {
            int slot = pp*4 + wv;
            int pre = 0;
            #pragma unroll
            for (int i = 0; i < 8; i++) pre += (i < slot) ? c8[i] : 0;
            if (v_act[pp]) {
                int idx = pre + v_rnk[pp];
                e0[idx] = make_float4(v_pr[pp], v_pc[pp], v_qa[pp], v_qb[pp]);
                e1[idx] = make_float4(v_qc[pp], v_ok[pp], 0.f, 0.f);
                int j = pp * 256 + t;
                tofs[g*TC + idx] = (unsigned)((s*NG + j) * EMBED);
            }
        }
        if (t == 0) tlen[g] = len;
        __syncthreads();

        // ---- w-scan: wave 0, lane = pixel, serial over culled list ----
        if (wv == 0) {
            int row = band*4 + (lane >> 4), col = chunk*16 + (lane & 15);
            float frow = (float)row, fcol = (float)col;
            float T = 1.f;
            float* wrow = w_ws + (size_t)g * (TC*64) + lane;
            #pragma unroll 2
            for (int k = 0; k < len; k++) {
                float4 A = e0[k];
                float4 B = e1[k];
                float dr = A.x - frow, dc = A.y - fcol;
                float pw = A.w*dr*dc - A.z*dr*dr - B.x*dc*dc;
                float aL = 0.f;
                if (pw <= 0.f) {
                    aL = fminf(B.y * __expf(pw), 0.99f);
                    aL = (aL >= AMIN) ? aL : 0.f;
                }
                wrow[k*64] = aL * T;
                T *= (1.f - aL);
            }
        }
    } else if (b < NTILES + 24) {
        // LDS-staged feature transpose: ft[s*NG+n][d] = feat[cam][d][hw], coalesced both sides
        __shared__ float l[EMBED * 73];
        int sc = b - NTILES;
        int s = sc / NCAM, cam = sc - s * NCAM;
        const float* src = a.feat[s] + cam * (EMBED * FHW);
        for (int i = t; i < EMBED * FHW; i += 256) {
            int d = i / FHW, hw = i - d * FHW;
            l[d * 73 + hw] = src[i];
        }
        __syncthreads();
        float* dst = ft + (s * NG + cam * FHW) * EMBED;
        for (int e = t; e < EMBED * FHW; e += 256) {
            int hw = e >> 7, d = e & 127;
            dst[hw * EMBED + d] = l[d * 73 + hw];
        }
    } else {
        __shared__ float red[256];
        float c = 0.f;
        for (int s = 0; s < 4; s++)
            for (int i = t; i < NG; i += 256)
                c += (a.opac[s][i] > THRESH) ? 1.f : 0.f;
        red[t] = c;
        __syncthreads();
        for (int st = 128; st > 0; st >>= 1) {
            if (t < st) red[t] += red[t + st];
            __syncthreads();
        }
        if (t == 0) out[6800000] = red[0];
    }
}

// K2: pure streaming weighted sum. block = (tile g, ch-block sub); wave = 8 channels.
// No syncthreads, no LDS, no serial chains: w precomputed, f rows wave-uniform.
__global__ __launch_bounds__(256) void render(const float* __restrict__ ft,
                                              const int* __restrict__ tlen,
                                              const unsigned* __restrict__ tofs,
                                              const float* __restrict__ w_ws,
                                              float* __restrict__ out)
{
    int gb = blockIdx.x, t = threadIdx.x;
    int g = gb >> 2, sub = gb & 3;
    int s, H, band, chunk;
    tile_decode(g, s, H, band, chunk);
    int P = H * H;
    float* o = out + ((s == 0) ? 0 : (s == 1) ? 80000 : (s == 2) ? 400000 : 1680000);
    int lane = t & 63, wv = t >> 6;
    int ch0 = __builtin_amdgcn_readfirstlane((sub * 4 + wv) * 8);
    int len = tlen[g];
    const unsigned* to = tofs + g * TC;
    const float* wr = w_ws + (size_t)g * (TC*64) + lane;

    float acc[8];
    #pragma unroll
    for (int i = 0; i < 8; i++) acc[i] = 0.f;

    #pragma unroll 4
    for (int k = 0; k < len; k++) {
        const float* fr = ft + to[k] + ch0;    // wave-uniform row -> scalar loads
        float wgt = wr[k * 64];                // coalesced 256B per k
        #pragma unroll
        for (int i = 0; i < 8; i++) acc[i] += wgt * fr[i];
    }

    int row = band*4 + (lane >> 4), col = chunk*16 + (lane & 15);
    if (row < H && col < H) {
        int pp = row * H + col;
        #pragma unroll
        for (int i = 0; i < 8; i++)
            o[(ch0 + i) * P + pp] = acc[i];
    }
}

extern "C" void kernel_launch(void* const* d_in, const int* in_sizes, int n_in,
                              void* d_out, int out_size, void* d_ws, size_t ws_size,
                              hipStream_t stream)
{
    Args a;
    for (int s = 0; s < 4; s++) {
        a.feat[s] = (const float*)d_in[4 * s + 0];
        a.mean[s] = (const float*)d_in[4 * s + 1];
        a.unc[s]  = (const float*)d_in[4 * s + 2];
        a.opac[s] = (const float*)d_in[4 * s + 3];
    }
    float* ws = (float*)d_ws;
    float*    ft    = ws;                          // 221,184 floats
    int*      tlen  = (int*)(ws + 221184);         // 891
    unsigned* tofs  = (unsigned*)(ws + 222080);    // 891*432 = 384,912
    float*    w_ws  = ws + 700000;                 // 891*432*64 floats ~ 98.5 MB

    prep<<<NTILES + 24 + 1, 256, 0, stream>>>(a, ft, tlen, tofs, w_ws, (float*)d_out);
    render<<<NTILES * 4, 256, 0, stream>>>(ft, tlen, tofs, w_ws, (float*)d_out);
}

// Round 9
// 34.400 us; speedup vs baseline: 1.2482x; 1.0747x over previous
//
#include <hip/hip_runtime.h>

#define NCAM   6
#define FHW    72        // FH*FW
#define EMBED  128
#define NG     432       // gaussians per scale
#define THRESH 0.01f
#define AMIN   (1.0f/255.0f)
#define NTILES 891
#define TC     432       // per-tile list capacity
// tiles are 4 rows x 16 cols:
// s0: 7x2=14 [0,14) H=25 | s1: 13x4=52 [14,66) H=50
// s2: 25x7=175 [66,241) H=100 | s3: 50x13=650 [241,891) H=200

struct Args {
    const float* feat[4];
    const float* mean[4];
    const float* unc[4];
    const float* opac[4];
};

__device__ __forceinline__ void tile_decode(int g, int& s, int& H, int& band, int& chunk)
{
    int tb;
    if (g < 14)       { s = 0; H = 25;  tb = g;       chunk = tb & 1;  band = tb >> 1; }
    else if (g < 66)  { s = 1; H = 50;  tb = g - 14;  chunk = tb & 3;  band = tb >> 2; }
    else if (g < 241) { s = 2; H = 100; tb = g - 66;  band = tb / 7;   chunk = tb - band * 7; }
    else              { s = 3; H = 200; tb = g - 241; band = tb / 13;  chunk = tb - band * 13; }
}

// K1: blocks [0,891) tile list+params+w-scan; [891,915) ft transpose; 915 count
// (unchanged from round 8 — proven correct)
__global__ __launch_bounds__(256) void prep(Args a, float* __restrict__ ft,
                                            int* __restrict__ tlen,
                                            unsigned* __restrict__ tofs,
                                            float* __restrict__ w_ws,
                                            float* __restrict__ out)
{
    int b = blockIdx.x, t = threadIdx.x;
    if (b < NTILES) {
        __shared__ float4 e0[TC];     // pr, pc, qa, qb
        __shared__ float4 e1[TC];     // qc, ok, -, -
        __shared__ int s_cnt[8];
        int g = b;
        int s, H, band, chunk;
        tile_decode(g, s, H, band, chunk);
        int lane = t & 63, wv = t >> 6;
        float sh = H * 0.01f;
        float r0f = (float)(band * 4), r1f = (float)min(band * 4 + 3, H - 1);
        float c0f = (float)(chunk * 16), c1f = (float)min(chunk * 16 + 15, H - 1);
        const float* mean = a.mean[s];
        const float* unc  = a.unc[s];
        const float* opac = a.opac[s];

        bool v_act[2]; int v_rnk[2];
        float v_pr[2], v_pc[2], v_qa[2], v_qb[2], v_qc[2], v_ok[2];
        #pragma unroll
        for (int pp = 0; pp < 2; pp++) {
            int j = pp * 256 + t;
            bool act = false;
            float pr = 0.f, pc = 0.f, qa = 0.f, qb = 0.f, qc = 0.f, ok = 0.f;
            if (j < NG) {
                float m0 = mean[j*3+0], m1 = mean[j*3+1];
                float u00 = fmaxf(unc[j*9+0], 1.f);
                float u01 = fmaxf(unc[j*9+1], 1.f);
                float u11 = fmaxf(unc[j*9+4], 1.f);
                float op = opac[j];
                pr = -sh*m1 + H*0.5f;
                pc = -sh*m0 + H*0.5f;
                float va = sh*sh*u11 + 0.3f;
                float vb = sh*sh*u01;
                float vc = sh*sh*u00 + 0.3f;
                float det = va*vc - vb*vb;
                if (op > THRESH && det > 0.f) {
                    float inv = 1.f/det;
                    qa = 0.5f*vc*inv;                      // dr^2 coeff
                    qc = 0.5f*va*inv;                      // dc^2 coeff
                    qb = vb*inv;                           // dr*dc coeff
                    ok = op;
                    float thr = __logf(255.f*op);          // alpha >= 1/255 level set
                    float Rr = sqrtf(2.f*va*thr) + 1e-2f;  // max |dr| on level set
                    float Rc = sqrtf(2.f*vc*thr) + 1e-2f;  // max |dc| on level set
                    act = (pr >= r0f-Rr) && (pr <= r1f+Rr) &&
                          (pc >= c0f-Rc) && (pc <= c1f+Rc);
                }
            }
            unsigned long long m = __ballot(act);
            v_act[pp] = act;
            v_rnk[pp] = __popcll(m & ((1ull << lane) - 1ull));
            v_pr[pp]=pr; v_pc[pp]=pc; v_qa[pp]=qa; v_qb[pp]=qb; v_qc[pp]=qc; v_ok[pp]=ok;
            if (lane == 0) s_cnt[pp*4 + wv] = __popcll(m);
        }
        __syncthreads();
        int c8[8];
        #pragma unroll
        for (int i = 0; i < 8; i++) c8[i] = s_cnt[i];
        int len = 0;
        #pragma unroll
        for (int i = 0; i < 8; i++) len += c8[i];
        #pragma unroll
        for (int pp = 0; pp < 2; pp++) {
            int slot = pp*4 + wv;
            int pre = 0;
            #pragma unroll
            for (int i = 0; i < 8; i++) pre += (i < slot) ? c8[i] : 0;
            if (v_act[pp]) {
                int idx = pre + v_rnk[pp];
                e0[idx] = make_float4(v_pr[pp], v_pc[pp], v_qa[pp], v_qb[pp]);
                e1[idx] = make_float4(v_qc[pp], v_ok[pp], 0.f, 0.f);
                int j = pp * 256 + t;
                tofs[g*TC + idx] = (unsigned)((s*NG + j) * EMBED);
            }
        }
        if (t == 0) tlen[g] = len;
        __syncthreads();

        // w-scan: wave 0, lane = pixel, serial over culled list
        if (wv == 0) {
            int row = band*4 + (lane >> 4), col = chunk*16 + (lane & 15);
            float frow = (float)row, fcol = (float)col;
            float T = 1.f;
            float* wrow = w_ws + (size_t)g * (TC*64) + lane;
            #pragma unroll 2
            for (int k = 0; k < len; k++) {
                float4 A = e0[k];
                float4 B = e1[k];
                float dr = A.x - frow, dc = A.y - fcol;
                float pw = A.w*dr*dc - A.z*dr*dr - B.x*dc*dc;
                float aL = 0.f;
                if (pw <= 0.f) {
                    aL = fminf(B.y * __expf(pw), 0.99f);
                    aL = (aL >= AMIN) ? aL : 0.f;
                }
                wrow[k*64] = aL * T;
                T *= (1.f - aL);
            }
        }
    } else if (b < NTILES + 24) {
        // LDS-staged feature transpose: ft[s*NG+n][d] = feat[cam][d][hw]
        __shared__ float l[EMBED * 73];
        int sc = b - NTILES;
        int s = sc / NCAM, cam = sc - s * NCAM;
        const float* src = a.feat[s] + cam * (EMBED * FHW);
        for (int i = t; i < EMBED * FHW; i += 256) {
            int d = i / FHW, hw = i - d * FHW;
            l[d * 73 + hw] = src[i];
        }
        __syncthreads();
        float* dst = ft + (s * NG + cam * FHW) * EMBED;
        for (int e = t; e < EMBED * FHW; e += 256) {
            int hw = e >> 7, d = e & 127;
            dst[hw * EMBED + d] = l[d * 73 + hw];
        }
    } else {
        __shared__ float red[256];
        float c = 0.f;
        for (int s = 0; s < 4; s++)
            for (int i = t; i < NG; i += 256)
                c += (a.opac[s][i] > THRESH) ? 1.f : 0.f;
        red[t] = c;
        __syncthreads();
        for (int st = 128; st > 0; st >>= 1) {
            if (t < st) red[t] += red[t + st];
            __syncthreads();
        }
        if (t == 0) out[6800000] = red[0];
    }
}

// K2: LDS-staged streaming weighted sum. block = (tile g, ch-split cs), CB channels.
// Chunk of 32 k's: stage w (coalesced) + f rows (contiguous 256B) into LDS, then
// k-loop is 1 conflict-free b32 + broadcast b128 reads + CPW FMAs. No global
// traffic in the hot loop; per-block serial path <= ~0.7us at every scale.
template<int CB>
__device__ __forceinline__ void render_seg(
    int g, int cs, int t,
    const float* __restrict__ ft, const int* __restrict__ tlen,
    const unsigned* __restrict__ tofs, const float* __restrict__ w_ws,
    float* __restrict__ out, float* s_w, float* s_f, unsigned* s_to)
{
    constexpr int CPW = CB / 4;       // channels per wave: 4, 8, 16
    constexpr int F4  = CB / 4;       // float4 per staged f row
    int s, H, band, chunk;
    tile_decode(g, s, H, band, chunk);
    int P = H * H;
    float* o = out + ((s == 0) ? 0 : (s == 1) ? 80000 : (s == 2) ? 400000 : 1680000);
    int lane = t & 63, wv = t >> 6;
    int ch0 = cs * CB;
    int len = tlen[g];
    const unsigned* to = tofs + g * TC;
    const float* wg = w_ws + (size_t)g * (TC * 64);

    for (int idx = t; idx < len; idx += 256) s_to[idx] = to[idx];

    float acc[CPW];
    #pragma unroll
    for (int i = 0; i < CPW; i++) acc[i] = 0.f;

    for (int c0 = 0; c0 < len; c0 += 32) {
        __syncthreads();                       // s_to ready / prev FMA done
        int nk = min(32, len - c0);
        for (int idx = t; idx < nk * 16; idx += 256) {
            int kk = idx >> 4, p4 = (idx & 15) << 2;
            *reinterpret_cast<float4*>(&s_w[kk * 64 + p4]) =
                *reinterpret_cast<const float4*>(&wg[(c0 + kk) * 64 + p4]);
        }
        for (int idx = t; idx < nk * F4; idx += 256) {
            int kk = idx / F4, c4 = (idx - kk * F4) * 4;
            *reinterpret_cast<float4*>(&s_f[kk * CB + c4]) =
                *reinterpret_cast<const float4*>(&ft[s_to[c0 + kk] + ch0 + c4]);
        }
        __syncthreads();
        #pragma unroll 2
        for (int k = 0; k < nk; k++) {
            float w = s_w[k * 64 + lane];
            const float* fr = &s_f[k * CB + wv * CPW];
            #pragma unroll
            for (int i = 0; i < CPW; i += 4) {
                float4 f = *reinterpret_cast<const float4*>(fr + i);
                acc[i]   += w * f.x; acc[i+1] += w * f.y;
                acc[i+2] += w * f.z; acc[i+3] += w * f.w;
            }
        }
    }

    int row = band * 4 + (lane >> 4), col = chunk * 16 + (lane & 15);
    if (row < H && col < H) {
        int pp = row * H + col;
        #pragma unroll
        for (int i = 0; i < CPW; i++)
            o[(ch0 + wv * CPW + i) * P + pp] = acc[i];
    }
}

// grid 2528: s0 [0,112) 8 splits x CB16 | s1 [112,528) 8 x CB16
//            s2 [528,1228) 4 x CB32     | s3 [1228,2528) 2 x CB64
__global__ __launch_bounds__(256) void render(const float* __restrict__ ft,
                                              const int* __restrict__ tlen,
                                              const unsigned* __restrict__ tofs,
                                              const float* __restrict__ w_ws,
                                              float* __restrict__ out)
{
    __shared__ float s_w[32 * 64];
    __shared__ float s_f[32 * 64];
    __shared__ unsigned s_to[TC];
    int bb = blockIdx.x, t = threadIdx.x;

    if (bb < 112) {
        render_seg<16>(bb >> 3, bb & 7, t, ft, tlen, tofs, w_ws, out, s_w, s_f, s_to);
    } else if (bb < 528) {
        int i = bb - 112;
        render_seg<16>(14 + (i >> 3), i & 7, t, ft, tlen, tofs, w_ws, out, s_w, s_f, s_to);
    } else if (bb < 1228) {
        int i = bb - 528;
        render_seg<32>(66 + (i >> 2), i & 3, t, ft, tlen, tofs, w_ws, out, s_w, s_f, s_to);
    } else {
        int i = bb - 1228;
        render_seg<64>(241 + (i >> 1), i & 1, t, ft, tlen, tofs, w_ws, out, s_w, s_f, s_to);
    }
}

extern "C" void kernel_launch(void* const* d_in, const int* in_sizes, int n_in,
                              void* d_out, int out_size, void* d_ws, size_t ws_size,
                              hipStream_t stream)
{
    Args a;
    for (int s = 0; s < 4; s++) {
        a.feat[s] = (const float*)d_in[4 * s + 0];
        a.mean[s] = (const float*)d_in[4 * s + 1];
        a.unc[s]  = (const float*)d_in[4 * s + 2];
        a.opac[s] = (const float*)d_in[4 * s + 3];
    }
    float* ws = (float*)d_ws;
    float*    ft    = ws;                          // 221,184 floats
    int*      tlen  = (int*)(ws + 221184);         // 891
    unsigned* tofs  = (unsigned*)(ws + 222080);    // 891*432
    float*    w_ws  = ws + 700000;                 // 891*432*64 floats (~98.5 MB)

    prep<<<NTILES + 24 + 1, 256, 0, stream>>>(a, ft, tlen, tofs, w_ws, (float*)d_out);
    render<<<2528, 256, 0, stream>>>(ft, tlen, tofs, w_ws, (float*)d_out);
}